// Round 7
// baseline (1365.459 us; speedup 1.0000x reference)
//
#include <hip/hip_runtime.h>
#include <hip/hip_bf16.h>

#define NPTS 200000
#define CIN 64
#define COUT 64
#define KVOL 27
#define NPAIRS 100000
#define NPAIRS_TOT (KVOL * NPAIRS)                       // 2,700,000
#define TROWS 64                                         // output rows per tile
#define NTILES (NPTS / TROWS)                            // 3125
#define NKEYS (NTILES * KVOL)                            // 84,375 (tile,k) buckets
#define SCAN_ITEMS 2048
#define NSCANB ((NKEYS + SCAN_ITEMS - 1) / SCAN_ITEMS)   // 42
#define CSTRIDE 128                                      // chunk descriptors per tile (mean ~81)
#define BN_EPS 1e-5f

static_assert(NPTS % TROWS == 0, "tiles");
static_assert(NSCANB <= 256, "single-block top scan");
static_assert(NPTS * CIN % (256 * 8) == 0, "fprep exact grid");
static_assert(NPAIRS_TOT < (1 << 22), "meta start pack");

typedef __attribute__((ext_vector_type(8))) short short8;   // 8 bf16 (4 VGPRs)
typedef __attribute__((ext_vector_type(4))) float f32x4;

__device__ inline ushort f2bf(float x) {
    union { __hip_bfloat16 h; ushort u; } cv;
    cv.h = __float2bfloat16(x);   // RNE
    return cv.u;
}

// ---------- preprocessing (counting sort by (out_tile64, k)) ----------

// feats fp32 [NPTS][64] -> bf16 [NPTS][64] (row = 128B)
__global__ __launch_bounds__(256) void fprep_kernel(const float* __restrict__ feats,
                                                    ushort* __restrict__ fbuf) {
    const int i = blockIdx.x * 256 + threadIdx.x;     // 8 elems/thread, exact grid
    const f32x4 v0 = *(const f32x4*)(feats + (size_t)i * 8);
    const f32x4 v1 = *(const f32x4*)(feats + (size_t)i * 8 + 4);
    short8 o;
    #pragma unroll
    for (int e = 0; e < 4; ++e) {
        o[e]     = (short)f2bf(v0[e]);
        o[e + 4] = (short)f2bf(v1[e]);
    }
    *(short8*)(fbuf + (size_t)i * 8) = o;
}

// W[k][cin][cout] fp32  ->  Wt[k][cout][cin] bf16 (B-frags load as 16B)
__global__ __launch_bounds__(256) void wprep_kernel(const float* __restrict__ wk,
                                                    ushort* __restrict__ wt) {
    const int i = blockIdx.x * 256 + threadIdx.x;     // over KVOL*64*64 = 110,592
    if (i >= KVOL * CIN * COUT) return;
    const int k = i >> 12, r = i & 4095, co = r >> 6, ci = r & 63;
    wt[i] = f2bf(wk[(k << 12) | (ci << 6) | co]);
}

// 2D grid: blockIdx.y = k
__global__ __launch_bounds__(256) void hist_kernel(const int* __restrict__ omap,
                                                   int* __restrict__ cnt) {
    const int k = blockIdx.y;
    const int i = blockIdx.x * 256 + threadIdx.x;
    if (i < NPAIRS)
        atomicAdd(&cnt[(omap[k * NPAIRS + i] >> 6) * KVOL + k], 1);
}

// 2-level exclusive scan over NKEYS counters.
__global__ __launch_bounds__(256) void scan1_kernel(const int* __restrict__ cnt,
                                                    int* __restrict__ offs,
                                                    int* __restrict__ bsum) {
    __shared__ int s[256];
    const int t = threadIdx.x;
    const int base = blockIdx.x * SCAN_ITEMS + t * 8;
    int v[8]; int sum = 0;
    #pragma unroll
    for (int i = 0; i < 8; ++i) {
        const int idx = base + i;
        v[i] = (idx < NKEYS) ? cnt[idx] : 0;
        sum += v[i];
    }
    s[t] = sum;
    __syncthreads();
    for (int off = 1; off < 256; off <<= 1) {         // Hillis-Steele inclusive
        const int x = (t >= off) ? s[t - off] : 0;
        __syncthreads();
        s[t] += x;
        __syncthreads();
    }
    if (t == 255) bsum[blockIdx.x] = s[255];
    int run = s[t] - sum;
    #pragma unroll
    for (int i = 0; i < 8; ++i) {
        const int idx = base + i;
        if (idx < NKEYS) offs[idx] = run;
        run += v[i];
    }
}

__global__ __launch_bounds__(256) void scan2_kernel(int* __restrict__ bsum) {
    __shared__ int s[256];
    const int t = threadIdx.x;
    const int v = (t < NSCANB) ? bsum[t] : 0;
    s[t] = v;
    __syncthreads();
    for (int off = 1; off < 256; off <<= 1) {
        const int x = (t >= off) ? s[t - off] : 0;
        __syncthreads();
        s[t] += x;
        __syncthreads();
    }
    if (t < NSCANB) bsum[t] = s[t] - v;
}

__global__ __launch_bounds__(256) void scan3_kernel(int* __restrict__ offs,
                                                    int* __restrict__ cursor,
                                                    const int* __restrict__ bsum) {
    const int base = blockIdx.x * SCAN_ITEMS + threadIdx.x * 8;
    const int add = bsum[blockIdx.x];
    if (blockIdx.x == 0 && threadIdx.x == 0) offs[NKEYS] = NPAIRS_TOT;  // sentinel
    #pragma unroll
    for (int i = 0; i < 8; ++i) {
        const int idx = base + i;
        if (idx < NKEYS) {
            const int v = offs[idx] + add;
            offs[idx] = v;
            cursor[idx] = v;
        }
    }
}

// payload = in_row (18b) | local_out_row (6b) << 18
__global__ __launch_bounds__(256) void fill_kernel(const int* __restrict__ imap,
                                                   const int* __restrict__ omap,
                                                   int* __restrict__ cursor,
                                                   unsigned* __restrict__ payload) {
    const int k = blockIdx.y;
    const int i = blockIdx.x * 256 + threadIdx.x;
    if (i < NPAIRS) {
        const int o = omap[k * NPAIRS + i];
        const int key = (o >> 6) * KVOL + k;
        const int pos = atomicAdd(&cursor[key], 1);
        payload[pos] = (unsigned)imap[k * NPAIRS + i] | ((unsigned)(o & 63) << 18);
    }
}

// Expand offs into flat per-tile chunk descriptors so the conv kernel needs ZERO
// dynamic walk (R6 post-mortem: the shfl/branch bucket walk — or R3/R4's per-k
// barriers — sat on every chunk's critical path; R0's plain sequential loop is the
// only structure that streamed). desc = start(22b) | k(5b)<<22 | cnt(5b)<<27.
// One wave per tile; lane l<27 owns bucket k=l.
__global__ __launch_bounds__(256) void chunkify_kernel(const int* __restrict__ offs,
                                                       unsigned* __restrict__ cmeta,
                                                       int* __restrict__ ntc) {
    const int wave = threadIdx.x >> 6, lane = threadIdx.x & 63;
    const int t = blockIdx.x * 4 + wave;
    if (t >= NTILES) return;
    int e0 = 0, c = 0;
    if (lane < KVOL) {
        e0 = offs[t * KVOL + lane];
        c  = offs[t * KVOL + lane + 1] - e0;
    }
    int nch = (c + 15) >> 4;
    int incl = nch;                                   // inclusive scan over 64 lanes
    #pragma unroll
    for (int off = 1; off < 64; off <<= 1) {
        const int y = __shfl_up(incl, off);
        if (lane >= off) incl += y;
    }
    const int excl = incl - nch;
    if (lane == KVOL - 1) ntc[t] = incl;              // total chunks for tile
    unsigned* dst = cmeta + t * CSTRIDE + excl;
    for (int i = 0; i < nch; ++i) {
        const int cnt = c - i * 16 > 16 ? 16 : c - i * 16;
        dst[i] = (unsigned)(e0 + i * 16) | ((unsigned)lane << 22) | ((unsigned)cnt << 27);
    }
}

// ---------- output-stationary conv, R0-shaped inner loop ----------
// Block = one 64-row tile (LDS [64][65] f32), 4 waves split the tile's chunk list
// into contiguous spans (sequential meta+payload reads, W amortized over k-runs).
// Per chunk: 1 meta load, 1 payload load, 2 feats gathers, 8 MFMA, 16 guarded
// LDS ds_adds. No barriers, no shfl-walk. Epilogue: BN fold + ReLU, one write.
__global__ __launch_bounds__(256) void conv_gather_kernel(
    const ushort* __restrict__ fbuf,      // bf16 feats [NPTS][64]
    const ushort* __restrict__ wt,        // bf16 [KVOL][COUT][CIN]
    const unsigned* __restrict__ payload,
    const unsigned* __restrict__ cmeta,
    const int* __restrict__ ntc,
    const float* __restrict__ gamma,
    const float* __restrict__ beta,
    const float* __restrict__ rmean,
    const float* __restrict__ rvar,
    float* __restrict__ out)
{
    __shared__ float tile[TROWS * 65];    // 16.64 KB
    const int lane = threadIdx.x & 63;
    const int wave = threadIdx.x >> 6;
    const int m = lane & 15;
    const int q = lane >> 4;
    const int t = blockIdx.x;

    for (int i = threadIdx.x; i < TROWS * 65; i += 256) tile[i] = 0.f;
    __syncthreads();

    const int nch = ntc[t];
    const int per = (nch + 3) >> 2;
    const int j1e = (wave + 1) * per;
    const int j1 = j1e < nch ? j1e : nch;

    int kcur = -1;
    short8 W0[4], W1[4];

    #pragma unroll 1
    for (int j = wave * per; j < j1; ++j) {
        const unsigned me = cmeta[t * CSTRIDE + j];
        const int mk = (int)((me >> 22) & 31u);
        const int mc = (int)(me >> 27);
        unsigned idx = (me & 0x3FFFFFu) + (unsigned)m;
        if (idx > NPAIRS_TOT - 1) idx = NPAIRS_TOT - 1;   // global tail only
        const unsigned pl = payload[idx];
        const ushort* fr = fbuf + (size_t)(pl & 0x3FFFFu) * 64 + q * 8;
        const short8 a0 = *(const short8*)(fr);
        const short8 a1 = *(const short8*)(fr + 32);

        if (mk != kcur) {                 // wave-uniform; runs of ~2.2 chunks per k
            const ushort* wb = wt + (mk << 12);
            #pragma unroll
            for (int nt = 0; nt < 4; ++nt) {
                W0[nt] = *(const short8*)(wb + (nt * 16 + m) * 64 + q * 8);
                W1[nt] = *(const short8*)(wb + (nt * 16 + m) * 64 + 32 + q * 8);
            }
            kcur = mk;
        }

        unsigned plr[4];
        #pragma unroll
        for (int r = 0; r < 4; ++r) plr[r] = (unsigned)__shfl((int)pl, q * 4 + r);

        f32x4 acc[4];
        #pragma unroll
        for (int nt = 0; nt < 4; ++nt) acc[nt] = (f32x4){0.f, 0.f, 0.f, 0.f};
        #pragma unroll
        for (int nt = 0; nt < 4; ++nt) {
            acc[nt] = __builtin_amdgcn_mfma_f32_16x16x32_bf16(a0, W0[nt], acc[nt], 0, 0, 0);
            acc[nt] = __builtin_amdgcn_mfma_f32_16x16x32_bf16(a1, W1[nt], acc[nt], 0, 0, 0);
        }

        #pragma unroll
        for (int r = 0; r < 4; ++r) {
            if (q * 4 + r < mc) {
                const int l = (int)((plr[r] >> 18) & 63u);
                #pragma unroll
                for (int nt = 0; nt < 4; ++nt)
                    atomicAdd(&tile[l * 65 + nt * 16 + m], acc[nt][r]);
            }
        }
    }

    __syncthreads();                                  // all waves' ds_adds done
    const int col = (threadIdx.x * 4) & 63;           // 4 fixed cols per thread
    float sc4[4], bi4[4];
    #pragma unroll
    for (int e = 0; e < 4; ++e) {
        const float sc = gamma[col + e] * rsqrtf(rvar[col + e] + BN_EPS);
        sc4[e] = sc;
        bi4[e] = beta[col + e] - rmean[col + e] * sc;
    }
    #pragma unroll
    for (int p = 0; p < 4; ++p) {
        const int row = p * 16 + (threadIdx.x >> 4);
        f32x4 o;
        #pragma unroll
        for (int e = 0; e < 4; ++e)
            o[e] = fmaxf(tile[row * 65 + col + e] * sc4[e] + bi4[e], 0.f);
        *(f32x4*)(out + ((size_t)t * TROWS + row) * COUT + col) = o;
    }
}

extern "C" void kernel_launch(void* const* d_in, const int* in_sizes, int n_in,
                              void* d_out, int out_size, void* d_ws, size_t ws_size,
                              hipStream_t stream) {
    const float* feats = (const float*)d_in[0];
    const float* wk    = (const float*)d_in[1];
    const float* gamma = (const float*)d_in[2];
    const float* beta  = (const float*)d_in[3];
    const float* rmean = (const float*)d_in[4];
    const float* rvar  = (const float*)d_in[5];
    const int* imap    = (const int*)d_in[6];
    const int* omap    = (const int*)d_in[7];
    float* out         = (float*)d_out;

    // workspace carve — byte-verified disjoint:
    //   cnt     [0         ,    337,500)
    //   offs    [1,048,576 ,  1,386,080)   (NKEYS+1 ints)
    //   bsum    [1,572,864 ,  1,573,032)
    //   cursor  [2,097,152 ,  2,434,652)
    //   wt      [3,145,728 ,  3,366,912)
    //   ntc     [3,670,016 ,  3,682,516)
    //   cmeta   [4,194,304 ,  5,794,304)   (3125*128*4B = 1.6MB)
    //   payload [6,291,456 , 17,091,456)   (10.8MB)
    //   fbuf    [18,874,368, 44,474,368)   (25.6MB; ws >= 51.2MB per R0)
    char* ws = (char*)d_ws;
    int* cnt          = (int*)(ws);
    int* offs         = (int*)(ws + (1u << 20));
    int* bsum         = (int*)(ws + 1572864u);
    int* cursor       = (int*)(ws + (2u << 20));
    ushort* wt        = (ushort*)(ws + (3u << 20));
    int* ntc          = (int*)(ws + 3670016u);
    unsigned* cmeta   = (unsigned*)(ws + (4u << 20));
    unsigned* payload = (unsigned*)(ws + (6u << 20));
    ushort* fbuf      = (ushort*)(ws + (18u << 20));

    hipMemsetAsync(cnt, 0, NKEYS * sizeof(int), stream);
    fprep_kernel<<<NPTS * CIN / (256 * 8), 256, 0, stream>>>(feats, fbuf);
    wprep_kernel<<<(KVOL * CIN * COUT + 255) / 256, 256, 0, stream>>>(wk, wt);
    hist_kernel<<<dim3((NPAIRS + 255) / 256, KVOL), 256, 0, stream>>>(omap, cnt);
    scan1_kernel<<<NSCANB, 256, 0, stream>>>(cnt, offs, bsum);
    scan2_kernel<<<1, 256, 0, stream>>>(bsum);
    scan3_kernel<<<NSCANB, 256, 0, stream>>>(offs, cursor, bsum);
    fill_kernel<<<dim3((NPAIRS + 255) / 256, KVOL), 256, 0, stream>>>(imap, omap, cursor, payload);
    chunkify_kernel<<<(NTILES + 3) / 4, 256, 0, stream>>>(offs, cmeta, ntc);
    conv_gather_kernel<<<NTILES, 256, 0, stream>>>(
        fbuf, wt, payload, cmeta, ntc, gamma, beta, rmean, rvar, out);
}

// Round 8
// 683.618 us; speedup vs baseline: 1.9974x; 1.9974x over previous
//
#include <hip/hip_runtime.h>
#include <hip/hip_bf16.h>

#define NPTS 200000
#define CIN 64
#define COUT 64
#define KVOL 27
#define NPAIRS 100000
#define GROUPS_PER_K (NPAIRS / 16)                                               // 6250 (exact)
#define GROUPS_PER_BLOCK 64
#define CHUNKS_PER_K ((GROUPS_PER_K + GROUPS_PER_BLOCK - 1) / GROUPS_PER_BLOCK)  // 98
#define BN_EPS 1e-5f

static_assert(NPAIRS % 16 == 0, "full chunks");
static_assert(NPTS * CIN % (256 * 8) == 0, "fprep exact grid");
static_assert((size_t)NPTS * COUT * 2 * 2 <= 51200000, "accum+fbuf fit in R0 ws");

typedef __attribute__((ext_vector_type(8))) short short8;   // 8 bf16 (4 VGPRs)
typedef __attribute__((ext_vector_type(4))) float f32x4;

__device__ inline ushort f2bf(float x) {
    union { __hip_bfloat16 h; ushort u; } cv;
    cv.h = __float2bfloat16(x);   // RNE
    return cv.u;
}

// packed bf16x2 global atomic add (global_atomic_pk_add_bf16)
__device__ inline void pk_atomic(ushort* p, float lo, float hi) {
    union { uint u; __hip_bfloat162 h; } cv;
    cv.u = (uint)f2bf(lo) | ((uint)f2bf(hi) << 16);
    unsafeAtomicAdd((__hip_bfloat162*)p, cv.h);
}

// ---------- feats fp32 -> bf16 (halves gather bytes; row = 128B = 1 line) ----------
__global__ __launch_bounds__(256) void fprep_kernel(const float* __restrict__ feats,
                                                    ushort* __restrict__ fbuf) {
    const int i = blockIdx.x * 256 + threadIdx.x;     // 8 elems/thread, exact grid
    const f32x4 v0 = *(const f32x4*)(feats + (size_t)i * 8);
    const f32x4 v1 = *(const f32x4*)(feats + (size_t)i * 8 + 4);
    short8 o;
    #pragma unroll
    for (int e = 0; e < 4; ++e) {
        o[e]     = (short)f2bf(v0[e]);
        o[e + 4] = (short)f2bf(v1[e]);
    }
    *(short8*)(fbuf + (size_t)i * 8) = o;
}

// ---------- conv scatter: R0 structure + pk_bf16 atomics ----------
// R7 post-mortem: R3-R7 all collapse onto ~3.4 cy per LDS lane-atomic (675K/CU);
// R0 onto ~2.0 cy per GLOBAL f32 lane-atomic. Scatter atomic op-count is the wall.
// This kernel: R0's proven loop (no sort, no barriers) with the 64 f32 lane-adds
// per pair replaced by 32 pk_add_bf16 lane-ops (2 couts per op; adjacent couts sit
// in adjacent lanes m,m^1 -> one shfl_xor(1) DPP pairs them; even lanes carry rows
// r=0,1, odd lanes r=2,3 -> all 8 atomic instrs/chunk have 64 active lanes).
//  A[m=lane&15][k=q*8+e]; B[k][j=lane&15]; D: pair=q*4+r, cout=nt*16+(lane&15).
__global__ __launch_bounds__(256) void conv_scatter_kernel(
    const ushort* __restrict__ fbuf,      // bf16 [NPTS][CIN]
    const float* __restrict__ wk,         // fp32 [KVOL][CIN][COUT]
    const int* __restrict__ imap,         // [KVOL][NPAIRS]
    const int* __restrict__ omap,         // [KVOL][NPAIRS]
    ushort* __restrict__ accum)           // bf16 [NPTS][COUT]
{
    const int koff  = blockIdx.x / CHUNKS_PER_K;
    const int chunk = blockIdx.x % CHUNKS_PER_K;
    const int lane  = threadIdx.x & 63;
    const int wave  = threadIdx.x >> 6;
    const int m     = lane & 15;
    const int q     = lane >> 4;

    // W[koff] fragments (fp32 -> bf16) once per block; amortized over 64 groups.
    short8 bfrag[2][4];
    const float* wbase = wk + koff * (CIN * COUT);
    #pragma unroll
    for (int h = 0; h < 2; ++h)
        #pragma unroll
        for (int nt = 0; nt < 4; ++nt)
            #pragma unroll
            for (int e = 0; e < 8; ++e)
                bfrag[h][nt][e] = (short)f2bf(wbase[(h * 32 + q * 8 + e) * COUT + nt * 16 + m]);

    const int* im = imap + koff * NPAIRS;
    const int* om = omap + koff * NPAIRS;
    const bool ev = (m & 1) == 0;

    #pragma unroll 1
    for (int it = 0; it < GROUPS_PER_BLOCK / 4; ++it) {
        const int g = chunk * GROUPS_PER_BLOCK + it * 4 + wave;
        if (g >= GROUPS_PER_K) break;
        const int base = g * 16;

        const int row = im[base + m];
        const ushort* fr = fbuf + (size_t)row * CIN + q * 8;
        const short8 a0 = *(const short8*)(fr);
        const short8 a1 = *(const short8*)(fr + 32);

        int orow[4];
        #pragma unroll
        for (int r = 0; r < 4; ++r) orow[r] = om[base + q * 4 + r];

        f32x4 acc[4];
        #pragma unroll
        for (int nt = 0; nt < 4; ++nt) acc[nt] = (f32x4){0.f, 0.f, 0.f, 0.f};
        #pragma unroll
        for (int nt = 0; nt < 4; ++nt) {
            acc[nt] = __builtin_amdgcn_mfma_f32_16x16x32_bf16(a0, bfrag[0][nt], acc[nt], 0, 0, 0);
            acc[nt] = __builtin_amdgcn_mfma_f32_16x16x32_bf16(a1, bfrag[1][nt], acc[nt], 0, 0, 0);
        }

        // even lane m=2j: rows orow[0],orow[1]; odd lane m=2j+1: rows orow[2],orow[3]
        const size_t r0 = (size_t)(ev ? orow[0] : orow[2]) * COUT;
        const size_t r1 = (size_t)(ev ? orow[1] : orow[3]) * COUT;
        #pragma unroll
        for (int nt = 0; nt < 4; ++nt) {
            const float c0 = __shfl_xor(acc[nt][0], 1);   // partner lane m^1 (DPP)
            const float c1 = __shfl_xor(acc[nt][1], 1);
            const float c2 = __shfl_xor(acc[nt][2], 1);
            const float c3 = __shfl_xor(acc[nt][3], 1);
            // pk value = (cout 2j, cout 2j+1): even lane owns low, odd lane owns high
            const float s0lo = ev ? acc[nt][0] : c2,  s0hi = ev ? c0 : acc[nt][2];
            const float s1lo = ev ? acc[nt][1] : c3,  s1hi = ev ? c1 : acc[nt][3];
            const int cb = nt * 16 + (m & 14);
            pk_atomic(accum + r0 + cb, s0lo, s0hi);
            pk_atomic(accum + r1 + cb, s1lo, s1hi);
        }
    }
}

// ---------- BN (inference-folded) + ReLU; bf16 accum -> fp32 out ----------
__global__ __launch_bounds__(256) void bn_relu_kernel(
    const ushort* __restrict__ accum,
    const float* __restrict__ gamma,
    const float* __restrict__ beta,
    const float* __restrict__ rmean,
    const float* __restrict__ rvar,
    float* __restrict__ out)
{
    __shared__ float s_scale[COUT];
    __shared__ float s_bias[COUT];
    if (threadIdx.x < COUT) {
        const int c = threadIdx.x;
        const float sc = gamma[c] * rsqrtf(rvar[c] + BN_EPS);
        s_scale[c] = sc;
        s_bias[c]  = beta[c] - rmean[c] * sc;
    }
    __syncthreads();

    const size_t idx = ((size_t)blockIdx.x * 256 + threadIdx.x) * 8;   // exact grid
    const short8 v = *(const short8*)(accum + idx);
    const int c0 = (int)(idx & (COUT - 1));   // 8 | COUT: all 8 stay in-row
    f32x4 o0, o1;
    #pragma unroll
    for (int e = 0; e < 4; ++e) {
        union { uint u; float f; } lo, hi;
        lo.u = ((uint)(ushort)v[e]) << 16;
        hi.u = ((uint)(ushort)v[e + 4]) << 16;
        o0[e] = fmaxf(lo.f * s_scale[c0 + e]     + s_bias[c0 + e],     0.f);
        o1[e] = fmaxf(hi.f * s_scale[c0 + e + 4] + s_bias[c0 + e + 4], 0.f);
    }
    *(f32x4*)(out + idx)     = o0;
    *(f32x4*)(out + idx + 4) = o1;
}

extern "C" void kernel_launch(void* const* d_in, const int* in_sizes, int n_in,
                              void* d_out, int out_size, void* d_ws, size_t ws_size,
                              hipStream_t stream) {
    const float* feats = (const float*)d_in[0];
    const float* wk    = (const float*)d_in[1];
    const float* gamma = (const float*)d_in[2];
    const float* beta  = (const float*)d_in[3];
    const float* rmean = (const float*)d_in[4];
    const float* rvar  = (const float*)d_in[5];
    const int* imap    = (const int*)d_in[6];
    const int* omap    = (const int*)d_in[7];
    float* out         = (float*)d_out;

    // workspace: accum bf16 [0, 25,600,000) + fbuf bf16 [25,600,000, 51,200,000)
    // = exactly the 51.2MB R0 already used. (Sort pipeline deleted entirely.)
    ushort* accum = (ushort*)d_ws;
    ushort* fbuf  = (ushort*)((char*)d_ws + (size_t)NPTS * COUT * 2);

    hipMemsetAsync(accum, 0, (size_t)NPTS * COUT * sizeof(ushort), stream);
    fprep_kernel<<<NPTS * CIN / (256 * 8), 256, 0, stream>>>(feats, fbuf);
    conv_scatter_kernel<<<KVOL * CHUNKS_PER_K, 256, 0, stream>>>(fbuf, wk, imap, omap, accum);
    bn_relu_kernel<<<NPTS * COUT / (256 * 8), 256, 0, stream>>>(
        accum, gamma, beta, rmean, rvar, out);
}